// Round 6
// baseline (450.228 us; speedup 1.0000x reference)
//
#include <hip/hip_runtime.h>
#include <cmath>

typedef __attribute__((ext_vector_type(8))) short short8;
typedef __attribute__((ext_vector_type(4))) float f32x4;

#define B_   32
#define C_   64
#define T_   8192
#define H_   256
#define TT   96
#define NTB  86              // ceil(8192/96)

// LDS geometry (bytes). ONE sliding buffer reused by rs1 -> rs2 -> rs3 (in-place,
// barrier-separated: each conv holds its full output in accumulators before storing).
//   buf row r as rs1 <-> time t0-18+r  (rows 0..113)
//   buf row r as rs2 <-> time t0-2+r   (rows 0..97, stored after conv2 barrier)
//   buf row r as rs3 <-> time t0+r     (rows 0..95, fp32, stored after conv3 barrier)
#define RS_ROWB 528          // 256ch*2B + 16B pad (132 floats)
#define XS_ROWB 144          // 64ch*2B + 16B pad
#define BUF_OFF 0            // 114 rows * 528 = 60192
#define XS_OFF  60192        // xs [115 rows][144B], row r <-> time t0-19+r
#define LDS_BYTES (60192 + 115*144)   // 76752 -> 2 blocks/CU

// packed-A workspace (bytes): frag = ((tap*MT + mt)*KT + ck) * 1024
#define A1_SZ 98304          // 3*16*2 frags
#define A2_SZ 393216         // 3*16*8
#define A3_SZ 196608         // 3*8*8
#define AW_TOTAL (A1_SZ + A2_SZ + A3_SZ)

__device__ __forceinline__ unsigned short f2bf(float f) {
    unsigned u = __builtin_bit_cast(unsigned, f);
    u += 0x7fffu + ((u >> 16) & 1u);          // RNE
    return (unsigned short)(u >> 16);
}

// HW packed f32->bf16 (RNE): low16 = bf16(lo), high16 = bf16(hi)
__device__ __forceinline__ unsigned cvtpk(float lo, float hi) {
    unsigned r;
    asm("v_cvt_pk_bf16_f32 %0, %1, %2" : "=v"(r) : "v"(lo), "v"(hi));
    return r;
}

// ---- pack fp32 weights -> bf16 MFMA A-fragments in d_ws ----
__global__ void pack_w(const float* __restrict__ w1, const float* __restrict__ w2,
                       const float* __restrict__ w3, unsigned short* __restrict__ ws)
{
    int id = blockIdx.x * 256 + threadIdx.x;          // frag-lane id, 43008 total
    const float* w; int MT, KT, Cin; unsigned short* dst;
    if (id < 6144)       {             w = w1; MT = 16; KT = 2; Cin = 64;  dst = ws; }
    else if (id < 30720) { id -= 6144; w = w2; MT = 16; KT = 8; Cin = 256; dst = ws + A1_SZ/2; }
    else if (id < 43008) { id -= 30720; w = w3; MT = 8; KT = 8; Cin = 256; dst = ws + (A1_SZ+A2_SZ)/2; }
    else return;
    const int lane = id & 63;
    int f = id >> 6;
    const int kt = f % KT; f /= KT;
    const int mt = f % MT;
    const int tap = f / MT;
    const int h  = mt*16 + (lane & 15);               // A row (out-channel)
    const int c0 = kt*32 + (lane >> 4)*8;             // A k (in-channel), 8 consecutive
    unsigned short* o = dst + (size_t)id * 8;
    #pragma unroll
    for (int j = 0; j < 8; ++j)
        o[j] = f2bf(w[((size_t)(h*Cin + c0 + j))*3 + tap]);
}

__device__ __forceinline__ short8 ldA(const char* base, int frag, int lane) {
    return *(const short8*)(base + ((size_t)frag*64 + lane)*16);
}

__global__ __launch_bounds__(512, 4)
void arflow_mfma(const float* __restrict__ x,
                 const float* __restrict__ b_in, const float* __restrict__ b_mid,
                 const float* __restrict__ b_out,
                 const float* __restrict__ alpha, const float* __restrict__ beta,
                 const char* __restrict__ wpk,
                 float* __restrict__ out)
{
    __shared__ __align__(16) char lds[LDS_BYTES];
    unsigned short* xs = (unsigned short*)(lds + XS_OFF);
    char* buf = lds + BUF_OFF;

    const char* wA1 = wpk;
    const char* wA2 = wpk + A1_SZ;
    const char* wA3 = wpk + A1_SZ + A2_SZ;

    const int b   = blockIdx.y;
    const int t0  = blockIdx.x * TT;
    const int tid = threadIdx.x;
    const int lane = tid & 63;
    const int wid  = tid >> 6;
    const int l15 = lane & 15, l4 = lane >> 4;

    // ---------------- stage x -> xs bf16 (115 rows); zero buf rows 0,1 ----------------
    {
        const int rr = tid & 63, cg = tid >> 6;
        #pragma unroll
        for (int p = 0; p < 4; ++p) {
            const int c = cg*8 + p*2;
            const float* xc0 = x + ((size_t)b*C_ + c)*T_;
            const float* xc1 = xc0 + T_;
            {
                const int t = t0 - 19 + rr;
                float v0 = 0.f, v1 = 0.f;
                if (t >= 0 && t < T_) { v0 = xc0[t]; v1 = xc1[t]; }
                *(unsigned*)(&xs[rr*72 + c]) = cvtpk(v0, v1);
            }
            {
                const int r = rr + 64;
                if (r < 115) {
                    const int t = t0 - 19 + r;
                    float v0 = 0.f, v1 = 0.f;
                    if (t < T_) { v0 = xc0[t]; v1 = xc1[t]; }   // t >= 45 here
                    *(unsigned*)(&xs[r*72 + c]) = cvtpk(v0, v1);
                }
            }
        }
        if (tid < 264) ((unsigned*)buf)[tid] = 0u;   // rows 0,1 (never read for kept outputs)
    }
    __syncthreads();

    // ---- conv1: xs(64) -> rs1(256) in buf. Wave wid: mtiles {2wid,2wid+1} x all 7 ntiles.
    //      A1 x1 per block. K=6 (3 taps x 2 ck) ----
    {
        const int mt0 = wid*2;
        f32x4 acc[2][7];
        #pragma unroll
        for (int m = 0; m < 2; ++m) {
            const f32x4 bv = *(const f32x4*)(b_in + (mt0+m)*16 + l4*4);
            #pragma unroll
            for (int nt = 0; nt < 7; ++nt) acc[m][nt] = bv;
        }
        int nb[7];
        #pragma unroll
        for (int nt = 0; nt < 7; ++nt)
            nb[nt] = XS_OFF + (16*nt + l15)*XS_ROWB + l4*16;
        short8 Ab[2][2];
        #pragma unroll
        for (int m = 0; m < 2; ++m) Ab[0][m] = ldA(wA1, (mt0+m)*2, lane);
        #pragma unroll
        for (int kt = 0; kt < 6; ++kt) {
            const int cur = kt & 1;
            const int tap = kt >> 1, ck = kt & 1;
            if (kt < 5) {
                const int kn = kt+1, tapn = kn>>1, ckn = kn&1;
                #pragma unroll
                for (int m = 0; m < 2; ++m)
                    Ab[cur^1][m] = ldA(wA1, (tapn*16 + mt0+m)*2 + ckn, lane);
            }
            __builtin_amdgcn_s_setprio(1);
            #pragma unroll
            for (int nt = 0; nt < 7; ++nt) {
                const short8 Bf = *(const short8*)(lds + nb[nt] + tap*XS_ROWB + ck*64);
                #pragma unroll
                for (int m = 0; m < 2; ++m)
                    acc[m][nt] = __builtin_amdgcn_mfma_f32_16x16x32_bf16(Ab[cur][m], Bf, acc[m][nt], 0, 0, 0);
            }
            __builtin_amdgcn_s_setprio(0);
        }
        #pragma unroll
        for (int nt = 0; nt < 7; ++nt) {
            const int tt16 = 16*nt + l15;
            const int t = t0 - 16 + tt16;
            char* dst0 = buf + (2 + tt16)*RS_ROWB;
            #pragma unroll
            for (int m = 0; m < 2; ++m) {
                const f32x4 a = acc[m][nt];
                unsigned long long pk = 0ull;
                if (t >= 0)
                    pk = (unsigned long long)cvtpk(a.x, a.y)
                       | ((unsigned long long)cvtpk(a.z, a.w) << 32);
                *(unsigned long long*)(dst0 + ((mt0+m)*16 + l4*4)*2) = pk;
            }
        }
    }
    __syncthreads();

    // ---- conv2: rs1(256) -> rs2(256), IN-PLACE into buf. Wm=4/Wn=2 (nt 4/3). K=24 ----
    {
        const int mg = wid >> 1, ng = wid & 1;
        const int ntb = ng ? 4 : 0, ncnt = ng ? 3 : 4;
        f32x4 acc[4][4];
        #pragma unroll
        for (int m = 0; m < 4; ++m) {
            const f32x4 bv = *(const f32x4*)(b_mid + (mg*4+m)*16 + l4*4);
            #pragma unroll
            for (int nt = 0; nt < 4; ++nt) acc[m][nt] = bv;
        }
        int nb[4];
        #pragma unroll
        for (int nt = 0; nt < 4; ++nt)
            nb[nt] = BUF_OFF + (16*(ntb+nt) + l15)*RS_ROWB + l4*16;
        short8 Ab[2][4];
        #pragma unroll
        for (int m = 0; m < 4; ++m) Ab[0][m] = ldA(wA2, (mg*4+m)*8, lane);
        #pragma unroll
        for (int kt = 0; kt < 24; ++kt) {
            const int cur = kt & 1;
            const int tap = kt >> 3, ck = kt & 7;
            if (kt < 23) {
                const int kn = kt+1, tapn = kn>>3, ckn = kn&7;
                #pragma unroll
                for (int m = 0; m < 4; ++m)
                    Ab[cur^1][m] = ldA(wA2, (tapn*16 + mg*4+m)*8 + ckn, lane);
            }
            __builtin_amdgcn_s_setprio(1);
            #pragma unroll
            for (int nt = 0; nt < 4; ++nt) if (nt < ncnt) {
                const short8 Bf = *(const short8*)(lds + nb[nt] + tap*RS_ROWB + ck*64);
                #pragma unroll
                for (int m = 0; m < 4; ++m)
                    acc[m][nt] = __builtin_amdgcn_mfma_f32_16x16x32_bf16(Ab[cur][m], Bf, acc[m][nt], 0, 0, 0);
            }
            __builtin_amdgcn_s_setprio(0);
        }
        __syncthreads();                 // all rs1 reads done before in-place overwrite
        #pragma unroll
        for (int nt = 0; nt < 4; ++nt) if (nt < ncnt) {
            const int tt16 = 16*(ntb+nt) + l15;
            const int r2row = tt16 - 14;             // rs2 row <-> t0-2+row
            if (r2row >= 0) {
                const int t = t0 - 16 + tt16;
                char* dst0 = buf + r2row*RS_ROWB;
                #pragma unroll
                for (int m = 0; m < 4; ++m) {
                    const f32x4 a = acc[m][nt];
                    unsigned long long pk = 0ull;
                    if (t >= 0)
                        pk = (unsigned long long)cvtpk(a.x, a.y)
                           | ((unsigned long long)cvtpk(a.z, a.w) << 32);
                    *(unsigned long long*)(dst0 + ((mg*4+m)*16 + l4*4)*2) = pk;
                }
            }
        }
    }

    // ---- prefetch epilogue x into regs (global, no LDS dep; hides under conv3) ----
    float xv[12];
    {
        #pragma unroll
        for (int m = 0; m < 12; ++m) {
            const int g = tid + m*512;               // 6144 = 64c * 96t
            const int c = (int)((unsigned)g / 96u);
            const int tl = g - c*96;
            const int t = t0 + tl;
            xv[m] = (t < T_) ? x[((size_t)b*C_ + c)*T_ + t] : 0.f;
        }
    }
    __syncthreads();

    // ---- conv3: rs2(256) -> rs3(128, fp32), IN-PLACE into buf. Wm=4/Wn=2 (nt 3/3). K=24 ----
    {
        const int mg = wid >> 1;                     // 2 mtiles each (M=128)
        const int ng = wid & 1;
        const int ntb = ng * 3;
        f32x4 acc[2][3];
        #pragma unroll
        for (int m = 0; m < 2; ++m) {
            const f32x4 bv = *(const f32x4*)(b_out + (mg*2+m)*16 + l4*4);
            #pragma unroll
            for (int nt = 0; nt < 3; ++nt) acc[m][nt] = bv;
        }
        int nb[3];
        #pragma unroll
        for (int nt = 0; nt < 3; ++nt)
            nb[nt] = BUF_OFF + (16*(ntb+nt) + l15)*RS_ROWB + l4*16;
        short8 Ab[2][2];
        #pragma unroll
        for (int m = 0; m < 2; ++m) {
            Ab[0][m] = ldA(wA3, ((mg*2+m))*8 + 0, lane);   // kt=0: tap0 ck0
            Ab[1][m] = ldA(wA3, ((mg*2+m))*8 + 1, lane);   // kt=1: tap0 ck1
        }
        #pragma unroll
        for (int kt = 0; kt < 24; ++kt) {
            const int cur = kt & 1;
            const int tap = kt >> 3, ck = kt & 7;
            __builtin_amdgcn_s_setprio(1);
            #pragma unroll
            for (int nt = 0; nt < 3; ++nt) {
                const short8 Bf = *(const short8*)(lds + nb[nt] + tap*RS_ROWB + ck*64);
                #pragma unroll
                for (int m = 0; m < 2; ++m)
                    acc[m][nt] = __builtin_amdgcn_mfma_f32_16x16x32_bf16(Ab[cur][m], Bf, acc[m][nt], 0, 0, 0);
            }
            __builtin_amdgcn_s_setprio(0);
            if (kt + 2 < 24) {
                const int kn = kt+2, tapn = kn>>3, ckn = kn&7;
                #pragma unroll
                for (int m = 0; m < 2; ++m)
                    Ab[cur][m] = ldA(wA3, (tapn*8 + mg*2+m)*8 + ckn, lane);
            }
        }
        __syncthreads();                 // all rs2 reads done before in-place overwrite
        #pragma unroll
        for (int nt = 0; nt < 3; ++nt) {
            char* dst0 = buf + (16*(ntb+nt) + l15)*RS_ROWB;   // rs3 row <-> t0+row, fp32 [96][132f]
            #pragma unroll
            for (int m = 0; m < 2; ++m)
                *(f32x4*)(dst0 + ((mg*2+m)*16 + l4*4)*4) = acc[m][nt];
        }
    }
    __syncthreads();

    // ---- epilogue: z = exp(alpha*tanh(log_s)+beta)*x + t ----
    {
        const float* rs3f = (const float*)buf;
        #pragma unroll
        for (int m = 0; m < 12; ++m) {
            const int g = tid + m*512;
            const int c = (int)((unsigned)g / 96u);
            const int tl = g - c*96;
            const int t = t0 + tl;
            const float ls = rs3f[tl*132 + c];
            const float tv = rs3f[tl*132 + c + 64];
            // tanh(ls) = 1 - 2/(exp(2*ls)+1)
            const float e2 = __expf(2.f * ls);
            const float th = fmaf(-2.f, __builtin_amdgcn_rcpf(e2 + 1.f), 1.f);
            const float lsv = fmaf(alpha[c], th, beta[c]);
            if (t < T_)
                out[((size_t)b*C_ + c)*T_ + t] = fmaf(__expf(lsv), xv[m], tv);
        }
    }
}

extern "C" void kernel_launch(void* const* d_in, const int* in_sizes, int n_in,
                              void* d_out, int out_size, void* d_ws, size_t ws_size,
                              hipStream_t stream) {
    const float* x     = (const float*)d_in[0];
    const float* w_in  = (const float*)d_in[1];
    const float* b_in  = (const float*)d_in[2];
    const float* w_mid = (const float*)d_in[3];
    const float* b_mid = (const float*)d_in[4];
    const float* w_out = (const float*)d_in[5];
    const float* b_out = (const float*)d_in[6];
    const float* alpha = (const float*)d_in[7];
    const float* beta  = (const float*)d_in[8];
    float* out = (float*)d_out;

    if (ws_size < (size_t)AW_TOTAL) return;

    hipLaunchKernelGGL(pack_w, dim3(168), dim3(256), 0, stream,
                       w_in, w_mid, w_out, (unsigned short*)d_ws);
    hipLaunchKernelGGL(arflow_mfma, dim3(NTB, B_), dim3(512), 0, stream,
                       x, b_in, b_mid, b_out, alpha, beta, (const char*)d_ws, out);
}